// Round 17
// baseline (225.083 us; speedup 1.0000x reference)
//
#include <hip/hip_runtime.h>
#include <hip/hip_bf16.h>

#define IN_F   1024
#define OUT_F  1024
#define NCH    9
#define KDIM   9216               // 9 channels * 1024 features, channel-major
#define BATCH  8192
#define NELEM  (BATCH * OUT_F)

// ---- GEMM: 256x256 tile, BK=32, 8 waves (2M x 4N), 4-slot LDS ring,
// ---- TWO tiles per barrier (cross-tile read/MFMA overlap), K-split x2 ----
#define BM 256
#define BN 256
#define BK 32
#define KHALF 4608
#define NTK (KHALF / BK)          // 144 K-tiles per half
#define SLOT 16384                // u16 per ring slot: A 8192 | B 8192 (32 KiB)

typedef __attribute__((ext_vector_type(4)))  float  f32x4;
typedef __attribute__((ext_vector_type(8)))  __bf16 bf16x8;

typedef __attribute__((address_space(3))) unsigned short       lds_u16;
typedef const __attribute__((address_space(1))) unsigned short glb_u16;

__device__ inline unsigned short f2bf(float f) {
    union { float f; unsigned int u; } v; v.f = f;
    unsigned int u = v.u;
    unsigned int r = (u + 0x7FFFu + ((u >> 16) & 1u)) >> 16;   // RNE
    return (unsigned short)r;
}

// ---------------------------------------------------------------------------
// Kernel 1 (merged prep, r12-validated): blocks [0,4096) activations,
// [4096,8192) weights. Both outputs channel-major: X[row][c*1024 + f].
// ---------------------------------------------------------------------------
__global__ void prep_kernel(const float* __restrict__ x,
                            const float* __restrict__ bw,
                            const float* __restrict__ sw,
                            const float* __restrict__ sc,
                            unsigned short* __restrict__ A,
                            unsigned short* __restrict__ W) {
    const int bid = blockIdx.x;
    if (bid < 4096) {
        int idx = bid * 256 + threadIdx.x;               // r*128 + f8
        const float4* xp = (const float4*)(x + (size_t)idx * 8);
        float4 x0 = xp[0], x1 = xp[1];
        float xs[8] = {x0.x, x0.y, x0.z, x0.w, x1.x, x1.y, x1.z, x1.w};

        unsigned short vals[8][9];
#pragma unroll
        for (int e = 0; e < 8; ++e) {
            float v  = xs[e];
            float s  = v / (1.0f + __expf(-v));          // silu
            float t  = (v + 2.2f) * 2.5f;                // (x - g0)/h
            float jf = floorf(t);
            int   j  = (int)jf;
            float u  = t - jf;
            float u2 = u * u, u3 = u2 * u;
            float p0 = u3 * (1.0f / 6.0f);
            float p1 = (-3.0f * u3 + 3.0f * u2 + 3.0f * u + 1.0f) * (1.0f / 6.0f);
            float p2 = (3.0f * u3 - 6.0f * u2 + 4.0f) * (1.0f / 6.0f);
            float om = 1.0f - u;
            float p3 = om * om * om * (1.0f / 6.0f);
            bool valid = (v >= -2.2f) && (v < 2.2f);
#pragma unroll
            for (int c = 0; c < 8; ++c) {
                int p = j - c;
                float bv = 0.0f;
                if (valid)
                    bv = (p == 0) ? p0 : (p == 1) ? p1 : (p == 2) ? p2 : (p == 3) ? p3 : 0.0f;
                vals[e][c] = f2bf(bv);
            }
            vals[e][8] = f2bf(s);
        }

        int r = idx >> 7, f8 = idx & 127;
        unsigned short* base = A + (size_t)r * KDIM + f8 * 8;
#pragma unroll
        for (int c = 0; c < 9; ++c) {
            uint4 pk;
            pk.x = (unsigned int)vals[0][c] | ((unsigned int)vals[1][c] << 16);
            pk.y = (unsigned int)vals[2][c] | ((unsigned int)vals[3][c] << 16);
            pk.z = (unsigned int)vals[4][c] | ((unsigned int)vals[5][c] << 16);
            pk.w = (unsigned int)vals[6][c] | ((unsigned int)vals[7][c] << 16);
            *(uint4*)(base + (size_t)c * 1024) = pk;
        }
    } else {
        int idx = (bid - 4096) * 256 + threadIdx.x;      // o*1024 + f
        int o = idx >> 10, f = idx & 1023;
        float scale = sc[idx];
        const float4* swp = (const float4*)(sw + (size_t)idx * 8);
        float4 w0 = swp[0], w1 = swp[1];
        unsigned short* Wb = W + (size_t)o * KDIM + f;
        Wb[0 * 1024] = f2bf(w0.x * scale);
        Wb[1 * 1024] = f2bf(w0.y * scale);
        Wb[2 * 1024] = f2bf(w0.z * scale);
        Wb[3 * 1024] = f2bf(w0.w * scale);
        Wb[4 * 1024] = f2bf(w1.x * scale);
        Wb[5 * 1024] = f2bf(w1.y * scale);
        Wb[6 * 1024] = f2bf(w1.z * scale);
        Wb[7 * 1024] = f2bf(w1.w * scale);
        Wb[8 * 1024] = f2bf(bw[idx]);
    }
}

// ---------------------------------------------------------------------------
// Kernel 2: K-split ring GEMM, ONE barrier per TWO K-tiles.
// Iteration i (T=2i): stages tiles T+2,T+3 into the slot-pair read during
// iteration i-1 (barrier-separated -> DMA-safe), then computes tiles T
// (slot cs) and T+1 (slot cs+1) in ONE scheduling region — tile T+1's
// ds_reads overlap tile T's MFMAs (different slots, no dependency).
// Boundary vmcnt(0) retires loads issued ~4400cy earlier (~free), barrier.
// Swizzle: phys chunk = logical ^ ((row>>1)&3), both sides (0 conflicts).
// C/D 16x16: col=lane&15, row=(lane>>4)*4+r.
// ---------------------------------------------------------------------------
#define DECLS(q) \
    const int ci##q = (q) * 512 + tid; \
    const int lo##q = ci##q << 3; \
    const int rr##q = ci##q >> 2; \
    const int cl##q = (((ci##q & 3) ^ ((rr##q >> 1) & 3)) << 3); \
    const unsigned short* srcA##q = Ap + (size_t)(m0 + rr##q) * KDIM + kbase + cl##q; \
    const unsigned short* srcB##q = Wp + (size_t)(n0 + rr##q) * KDIM + kbase + cl##q;

#define STAGE_A(q, ns) do { \
    __builtin_amdgcn_global_load_lds((glb_u16*)srcA##q, (lds_u16*)(ns) + lo##q, 16, 0, 0); \
    srcA##q += BK; } while (0)

#define STAGE_B(q, ns) do { \
    __builtin_amdgcn_global_load_lds((glb_u16*)srcB##q, (lds_u16*)(ns) + 8192 + lo##q, 16, 0, 0); \
    srcB##q += BK; } while (0)

#define RDA(mi) (*(const bf16x8*)&sA[(rowa + (mi) * 16) * BK + koff])
#define RDB(ni) (*(const bf16x8*)&sB[(rowb + (ni) * 16) * BK + koff])

#define MM4(av, mi) \
    acc[mi][0] = __builtin_amdgcn_mfma_f32_16x16x32_bf16(av, b0, acc[mi][0], 0, 0, 0); \
    acc[mi][1] = __builtin_amdgcn_mfma_f32_16x16x32_bf16(av, b1, acc[mi][1], 0, 0, 0); \
    acc[mi][2] = __builtin_amdgcn_mfma_f32_16x16x32_bf16(av, b2, acc[mi][2], 0, 0, 0); \
    acc[mi][3] = __builtin_amdgcn_mfma_f32_16x16x32_bf16(av, b3, acc[mi][3], 0, 0, 0);

#define TILE_BODY(sbase) do { \
    const unsigned short* sA = lds + (sbase); \
    const unsigned short* sB = sA + 8192; \
    bf16x8 b0 = RDB(0), b1 = RDB(1), b2 = RDB(2), b3 = RDB(3); \
    __builtin_amdgcn_s_setprio(1); \
    bf16x8 a0 = RDA(0); MM4(a0, 0) \
    bf16x8 a1 = RDA(1); MM4(a1, 1) \
    bf16x8 a2 = RDA(2); MM4(a2, 2) \
    bf16x8 a3 = RDA(3); MM4(a3, 3) \
    bf16x8 a4 = RDA(4); MM4(a4, 4) \
    bf16x8 a5 = RDA(5); MM4(a5, 5) \
    bf16x8 a6 = RDA(6); MM4(a6, 6) \
    bf16x8 a7 = RDA(7); MM4(a7, 7) \
    __builtin_amdgcn_s_setprio(0); \
} while (0)

#define ITER(T, cs) do { \
    if ((T) + 2 < NTK) { \
        unsigned short* ns0 = lds + (((cs) ^ 2)) * SLOT; \
        STAGE_A(0, ns0); STAGE_A(1, ns0); STAGE_B(0, ns0); STAGE_B(1, ns0); \
    } \
    if ((T) + 3 < NTK) { \
        unsigned short* ns1 = lds + (((cs) ^ 2) + 1) * SLOT; \
        STAGE_A(0, ns1); STAGE_A(1, ns1); STAGE_B(0, ns1); STAGE_B(1, ns1); \
    } \
    TILE_BODY((cs) * SLOT); \
    TILE_BODY(((cs) + 1) * SLOT); \
    asm volatile("s_waitcnt vmcnt(0)" ::: "memory"); \
    __builtin_amdgcn_s_barrier(); \
} while (0)

__global__ __launch_bounds__(512, 2) void gemm_ring2(
    const unsigned short* __restrict__ Ap,
    const unsigned short* __restrict__ Wp,
    float* __restrict__ C, float* __restrict__ P, int mode) {
    __shared__ unsigned short lds[4 * SLOT];             // 128 KiB ring

    const int tid  = threadIdx.x;
    const int wave = tid >> 6;
    const int lane = tid & 63;
    const int lm16 = lane & 15;
    const int lhi  = lane >> 4;
    const int koff = ((lhi ^ ((lm16 >> 1) & 3)) << 3);   // conflict-free read

    const int bid  = blockIdx.x;
    const int mg   = bid & 3;
    const int kb   = (bid >> 2) & 1;
    const int j    = bid >> 3;
    const int m0   = (mg * 8 + (j >> 2)) * BM;
    const int n0   = (j & 3) * BN;
    const int kbase = kb * KHALF;

    const int wr = wave >> 2;                            // 0..1 (M)
    const int wc = wave & 3;                             // 0..3 (N)
    const int rowa = wr * 128 + lm16;
    const int rowb = wc * 64 + lm16;

    f32x4 acc[8][4];
#pragma unroll
    for (int i = 0; i < 8; ++i)
#pragma unroll
        for (int jn = 0; jn < 4; ++jn) acc[i][jn] = (f32x4)(0.0f);

    DECLS(0) DECLS(1)

    // prologue: stage tiles 0,1 into slots 0,1
    {
        unsigned short* ns = lds;
        STAGE_A(0, ns); STAGE_A(1, ns); STAGE_B(0, ns); STAGE_B(1, ns);
    }
    {
        unsigned short* ns = lds + SLOT;
        STAGE_A(0, ns); STAGE_A(1, ns); STAGE_B(0, ns); STAGE_B(1, ns);
    }
    asm volatile("s_waitcnt vmcnt(0)" ::: "memory");
    __builtin_amdgcn_s_barrier();

#pragma unroll 1
    for (int t2 = 0; t2 < NTK; t2 += 4) {
        ITER(t2, 0);                                     // tiles t2, t2+1   (slots 0,1)
        ITER(t2 + 2, 2);                                 // tiles t2+2, t2+3 (slots 2,3)
    }

    // epilogue: C/D layout col = lane&15, row = (lane>>4)*4 + r
    const int orow = m0 + wr * 128 + (lhi << 2);
    const int ocol = n0 + wc * 64 + lm16;
    if (mode) {
#pragma unroll
        for (int mi = 0; mi < 8; ++mi)
#pragma unroll
            for (int ni = 0; ni < 4; ++ni)
#pragma unroll
                for (int r = 0; r < 4; ++r)
                    atomicAdd(&C[(size_t)(orow + mi * 16 + r) * OUT_F + (ocol + ni * 16)], acc[mi][ni][r]);
    } else {
        float* dst = kb ? P : C;
#pragma unroll
        for (int mi = 0; mi < 8; ++mi)
#pragma unroll
            for (int ni = 0; ni < 4; ++ni)
#pragma unroll
                for (int r = 0; r < 4; ++r)
                    dst[(size_t)(orow + mi * 16 + r) * OUT_F + (ocol + ni * 16)] = acc[mi][ni][r];
    }
}

// ---------------------------------------------------------------------------
// Kernel 3: C += P (K-split reduction), float4.
// ---------------------------------------------------------------------------
__global__ void add_kernel(float* __restrict__ C, const float* __restrict__ P) {
    int i = blockIdx.x * blockDim.x + threadIdx.x;
    if (i >= NELEM / 4) return;
    f32x4* c4 = (f32x4*)C;
    const f32x4* p4 = (const f32x4*)P;
    c4[i] = c4[i] + p4[i];
}

// ---------------------------------------------------------------------------
extern "C" void kernel_launch(void* const* d_in, const int* in_sizes, int n_in,
                              void* d_out, int out_size, void* d_ws, size_t ws_size,
                              hipStream_t stream) {
    const float* x             = (const float*)d_in[0];
    const float* base_weight   = (const float*)d_in[1];
    const float* spline_weight = (const float*)d_in[2];
    const float* spline_scaler = (const float*)d_in[3];
    float* out = (float*)d_out;

    const size_t wbytes = (size_t)OUT_F * KDIM * 2;      // 18.9 MB
    const size_t abytes = (size_t)BATCH * KDIM * 2;      // 151 MB
    const size_t pbytes = (size_t)NELEM * 4;             // 33.5 MB
    unsigned short* Wc   = (unsigned short*)d_ws;
    unsigned short* Abuf = (unsigned short*)((char*)d_ws + wbytes);
    float*          P    = (float*)((char*)d_ws + wbytes + abytes);

    const int mode = (ws_size >= wbytes + abytes + pbytes) ? 0 : 1;
    if (mode == 1)
        (void)hipMemsetAsync(d_out, 0, pbytes, stream);  // atomic fallback needs zeroed C

    prep_kernel<<<8192, 256, 0, stream>>>(x, base_weight, spline_weight,
                                          spline_scaler, Abuf, Wc);

    gemm_ring2<<<256, 512, 0, stream>>>(Abuf, Wc, out, P, mode);

    if (mode == 0)
        add_kernel<<<(NELEM / 4 + 255) / 256, 256, 0, stream>>>(out, P);
}

// Round 18
// 198.947 us; speedup vs baseline: 1.1314x; 1.1314x over previous
//
#include <hip/hip_runtime.h>
#include <hip/hip_bf16.h>

#define IN_F   1024
#define OUT_F  1024
#define NCH    9
#define KDIM   9216               // 9 channels * 1024 features, channel-major
#define BATCH  8192
#define NELEM  (BATCH * OUT_F)

// ---- GEMM: 256x256 tile, BK=32, 8 waves (2M x 4N), 4-slot LDS ring, K-split x2 ----
#define BM 256
#define BN 256
#define BK 32
#define KHALF 4608
#define NTK (KHALF / BK)          // 144 K-tiles per half
#define SLOT 16384                // u16 per ring slot: A 8192 | B 8192 (32 KiB)

typedef __attribute__((ext_vector_type(4)))  float  f32x4;
typedef __attribute__((ext_vector_type(8)))  __bf16 bf16x8;

typedef __attribute__((address_space(3))) unsigned short       lds_u16;
typedef const __attribute__((address_space(1))) unsigned short glb_u16;

__device__ inline unsigned short f2bf(float f) {
    union { float f; unsigned int u; } v; v.f = f;
    unsigned int u = v.u;
    unsigned int r = (u + 0x7FFFu + ((u >> 16) & 1u)) >> 16;   // RNE
    return (unsigned short)r;
}

// ---------------------------------------------------------------------------
// Kernel 1 (merged prep, r12-validated): blocks [0,4096) activations,
// [4096,8192) weights. Both outputs channel-major: X[row][c*1024 + f].
// ---------------------------------------------------------------------------
__global__ void prep_kernel(const float* __restrict__ x,
                            const float* __restrict__ bw,
                            const float* __restrict__ sw,
                            const float* __restrict__ sc,
                            unsigned short* __restrict__ A,
                            unsigned short* __restrict__ W) {
    const int bid = blockIdx.x;
    if (bid < 4096) {
        int idx = bid * 256 + threadIdx.x;               // r*128 + f8
        const float4* xp = (const float4*)(x + (size_t)idx * 8);
        float4 x0 = xp[0], x1 = xp[1];
        float xs[8] = {x0.x, x0.y, x0.z, x0.w, x1.x, x1.y, x1.z, x1.w};

        unsigned short vals[8][9];
#pragma unroll
        for (int e = 0; e < 8; ++e) {
            float v  = xs[e];
            float s  = v / (1.0f + __expf(-v));          // silu
            float t  = (v + 2.2f) * 2.5f;                // (x - g0)/h
            float jf = floorf(t);
            int   j  = (int)jf;
            float u  = t - jf;
            float u2 = u * u, u3 = u2 * u;
            float p0 = u3 * (1.0f / 6.0f);
            float p1 = (-3.0f * u3 + 3.0f * u2 + 3.0f * u + 1.0f) * (1.0f / 6.0f);
            float p2 = (3.0f * u3 - 6.0f * u2 + 4.0f) * (1.0f / 6.0f);
            float om = 1.0f - u;
            float p3 = om * om * om * (1.0f / 6.0f);
            bool valid = (v >= -2.2f) && (v < 2.2f);
#pragma unroll
            for (int c = 0; c < 8; ++c) {
                int p = j - c;
                float bv = 0.0f;
                if (valid)
                    bv = (p == 0) ? p0 : (p == 1) ? p1 : (p == 2) ? p2 : (p == 3) ? p3 : 0.0f;
                vals[e][c] = f2bf(bv);
            }
            vals[e][8] = f2bf(s);
        }

        int r = idx >> 7, f8 = idx & 127;
        unsigned short* base = A + (size_t)r * KDIM + f8 * 8;
#pragma unroll
        for (int c = 0; c < 9; ++c) {
            uint4 pk;
            pk.x = (unsigned int)vals[0][c] | ((unsigned int)vals[1][c] << 16);
            pk.y = (unsigned int)vals[2][c] | ((unsigned int)vals[3][c] << 16);
            pk.z = (unsigned int)vals[4][c] | ((unsigned int)vals[5][c] << 16);
            pk.w = (unsigned int)vals[6][c] | ((unsigned int)vals[7][c] << 16);
            *(uint4*)(base + (size_t)c * 1024) = pk;
        }
    } else {
        int idx = (bid - 4096) * 256 + threadIdx.x;      // o*1024 + f
        int o = idx >> 10, f = idx & 1023;
        float scale = sc[idx];
        const float4* swp = (const float4*)(sw + (size_t)idx * 8);
        float4 w0 = swp[0], w1 = swp[1];
        unsigned short* Wb = W + (size_t)o * KDIM + f;
        Wb[0 * 1024] = f2bf(w0.x * scale);
        Wb[1 * 1024] = f2bf(w0.y * scale);
        Wb[2 * 1024] = f2bf(w0.z * scale);
        Wb[3 * 1024] = f2bf(w0.w * scale);
        Wb[4 * 1024] = f2bf(w1.x * scale);
        Wb[5 * 1024] = f2bf(w1.y * scale);
        Wb[6 * 1024] = f2bf(w1.z * scale);
        Wb[7 * 1024] = f2bf(w1.w * scale);
        Wb[8 * 1024] = f2bf(bw[idx]);
    }
}

// ---------------------------------------------------------------------------
// Kernel 2 (r7 champion, verbatim): K-split ring GEMM, ONE barrier per K-tile.
// 4-slot LDS ring (BK=32): tile t computes slot t&3, stages tile t+3 into
// slot (t+3)&3 (== slot t-1, last read before the barrier that opened tile
// t). Counted vmcnt(8) at tile end (t+2,t+3 in flight; never 0 until tail).
// Reads and MFMAs in ONE scheduling region (compiler emits fine lgkmcnt).
// Swizzle: phys chunk = logical ^ ((row>>1)&3), both sides (0 conflicts).
// ---------------------------------------------------------------------------
#define DECLS(q) \
    const int ci##q = (q) * 512 + tid; \
    const int lo##q = ci##q << 3; \
    const int rr##q = ci##q >> 2; \
    const int cl##q = (((ci##q & 3) ^ ((rr##q >> 1) & 3)) << 3); \
    const unsigned short* srcA##q = Ap + (size_t)(m0 + rr##q) * KDIM + kbase + cl##q; \
    const unsigned short* srcB##q = Wp + (size_t)(n0 + rr##q) * KDIM + kbase + cl##q;

#define STAGE_A(q, ns) do { \
    __builtin_amdgcn_global_load_lds((glb_u16*)srcA##q, (lds_u16*)(ns) + lo##q, 16, 0, 0); \
    srcA##q += BK; } while (0)

#define STAGE_B(q, ns) do { \
    __builtin_amdgcn_global_load_lds((glb_u16*)srcB##q, (lds_u16*)(ns) + 8192 + lo##q, 16, 0, 0); \
    srcB##q += BK; } while (0)

#define RDA(mi) (*(const bf16x8*)&sA[(rowa + (mi) * 16) * BK + koff])
#define RDB(ni) (*(const bf16x8*)&sB[(rowb + (ni) * 16) * BK + koff])

#define MM4(av, mi) \
    acc[mi][0] = __builtin_amdgcn_mfma_f32_16x16x32_bf16(av, b0, acc[mi][0], 0, 0, 0); \
    acc[mi][1] = __builtin_amdgcn_mfma_f32_16x16x32_bf16(av, b1, acc[mi][1], 0, 0, 0); \
    acc[mi][2] = __builtin_amdgcn_mfma_f32_16x16x32_bf16(av, b2, acc[mi][2], 0, 0, 0); \
    acc[mi][3] = __builtin_amdgcn_mfma_f32_16x16x32_bf16(av, b3, acc[mi][3], 0, 0, 0);

__global__ __launch_bounds__(512, 2) void gemm_ring(
    const unsigned short* __restrict__ Ap,
    const unsigned short* __restrict__ Wp,
    float* __restrict__ C, float* __restrict__ P, int mode) {
    __shared__ unsigned short lds[4 * SLOT];             // 128 KiB ring

    const int tid  = threadIdx.x;
    const int wave = tid >> 6;
    const int lane = tid & 63;
    const int lm16 = lane & 15;
    const int lhi  = lane >> 4;
    const int koff = ((lhi ^ ((lm16 >> 1) & 3)) << 3);   // conflict-free read

    const int bid  = blockIdx.x;
    const int mg   = bid & 3;
    const int kb   = (bid >> 2) & 1;
    const int j    = bid >> 3;
    const int m0   = (mg * 8 + (j >> 2)) * BM;
    const int n0   = (j & 3) * BN;
    const int kbase = kb * KHALF;

    const int wr = wave >> 2;                            // 0..1 (M)
    const int wc = wave & 3;                             // 0..3 (N)
    const int rowa = wr * 128 + lm16;
    const int rowb = wc * 64 + lm16;

    f32x4 acc[8][4];
#pragma unroll
    for (int i = 0; i < 8; ++i)
#pragma unroll
        for (int jn = 0; jn < 4; ++jn) acc[i][jn] = (f32x4)(0.0f);

    DECLS(0) DECLS(1)

    // prologue: stage tiles 0,1,2 into slots 0,1,2
    {
        unsigned short* ns = lds;
        STAGE_A(0, ns); STAGE_A(1, ns); STAGE_B(0, ns); STAGE_B(1, ns);
    }
    {
        unsigned short* ns = lds + SLOT;
        STAGE_A(0, ns); STAGE_A(1, ns); STAGE_B(0, ns); STAGE_B(1, ns);
    }
    {
        unsigned short* ns = lds + 2 * SLOT;
        STAGE_A(0, ns); STAGE_A(1, ns); STAGE_B(0, ns); STAGE_B(1, ns);
    }
    asm volatile("s_waitcnt vmcnt(8)" ::: "memory");     // tile 0 landed
    __builtin_amdgcn_s_barrier();

#pragma unroll 4
    for (int t = 0; t < NTK; ++t) {
        const unsigned short* sA = lds + (t & 3) * SLOT;
        const unsigned short* sB = sA + 8192;
        unsigned short* ns = lds + ((t + 3) & 3) * SLOT;

        if (t + 3 < NTK) { STAGE_A(0, ns); STAGE_A(1, ns); STAGE_B(0, ns); STAGE_B(1, ns); }

        // one scheduling region: compiler pipelines ds_read -> MFMA per-fragment
        bf16x8 b0 = RDB(0), b1 = RDB(1), b2 = RDB(2), b3 = RDB(3);
        __builtin_amdgcn_s_setprio(1);
        bf16x8 a0 = RDA(0); MM4(a0, 0)
        bf16x8 a1 = RDA(1); MM4(a1, 1)
        bf16x8 a2 = RDA(2); MM4(a2, 2)
        bf16x8 a3 = RDA(3); MM4(a3, 3)
        bf16x8 a4 = RDA(4); MM4(a4, 4)
        bf16x8 a5 = RDA(5); MM4(a5, 5)
        bf16x8 a6 = RDA(6); MM4(a6, 6)
        bf16x8 a7 = RDA(7); MM4(a7, 7)
        __builtin_amdgcn_s_setprio(0);

        // tile boundary: counted wait (tile t+1 landed; t+2,t+3 in flight)
        if (t <= NTK - 4)      asm volatile("s_waitcnt vmcnt(8)" ::: "memory");
        else if (t == NTK - 3) asm volatile("s_waitcnt vmcnt(4)" ::: "memory");
        else                   asm volatile("s_waitcnt vmcnt(0)" ::: "memory");
        __builtin_amdgcn_s_barrier();
    }

    // epilogue: C/D layout col = lane&15, row = (lane>>4)*4 + r
    const int orow = m0 + wr * 128 + (lhi << 2);
    const int ocol = n0 + wc * 64 + lm16;
    if (mode) {
#pragma unroll
        for (int mi = 0; mi < 8; ++mi)
#pragma unroll
            for (int ni = 0; ni < 4; ++ni)
#pragma unroll
                for (int r = 0; r < 4; ++r)
                    atomicAdd(&C[(size_t)(orow + mi * 16 + r) * OUT_F + (ocol + ni * 16)], acc[mi][ni][r]);
    } else {
        float* dst = kb ? P : C;
#pragma unroll
        for (int mi = 0; mi < 8; ++mi)
#pragma unroll
            for (int ni = 0; ni < 4; ++ni)
#pragma unroll
                for (int r = 0; r < 4; ++r)
                    dst[(size_t)(orow + mi * 16 + r) * OUT_F + (ocol + ni * 16)] = acc[mi][ni][r];
    }
}

// ---------------------------------------------------------------------------
// Kernel 3: C += P (K-split reduction), float4.
// ---------------------------------------------------------------------------
__global__ void add_kernel(float* __restrict__ C, const float* __restrict__ P) {
    int i = blockIdx.x * blockDim.x + threadIdx.x;
    if (i >= NELEM / 4) return;
    f32x4* c4 = (f32x4*)C;
    const f32x4* p4 = (const f32x4*)P;
    c4[i] = c4[i] + p4[i];
}

// ---------------------------------------------------------------------------
extern "C" void kernel_launch(void* const* d_in, const int* in_sizes, int n_in,
                              void* d_out, int out_size, void* d_ws, size_t ws_size,
                              hipStream_t stream) {
    const float* x             = (const float*)d_in[0];
    const float* base_weight   = (const float*)d_in[1];
    const float* spline_weight = (const float*)d_in[2];
    const float* spline_scaler = (const float*)d_in[3];
    float* out = (float*)d_out;

    const size_t wbytes = (size_t)OUT_F * KDIM * 2;      // 18.9 MB
    const size_t abytes = (size_t)BATCH * KDIM * 2;      // 151 MB
    const size_t pbytes = (size_t)NELEM * 4;             // 33.5 MB
    unsigned short* Wc   = (unsigned short*)d_ws;
    unsigned short* Abuf = (unsigned short*)((char*)d_ws + wbytes);
    float*          P    = (float*)((char*)d_ws + wbytes + abytes);

    const int mode = (ws_size >= wbytes + abytes + pbytes) ? 0 : 1;
    if (mode == 1)
        (void)hipMemsetAsync(d_out, 0, pbytes, stream);  // atomic fallback needs zeroed C

    prep_kernel<<<8192, 256, 0, stream>>>(x, base_weight, spline_weight,
                                          spline_scaler, Abuf, Wc);

    gemm_ring<<<256, 512, 0, stream>>>(Abuf, Wc, out, P, mode);

    if (mode == 0)
        add_kernel<<<(NELEM / 4 + 255) / 256, 256, 0, stream>>>(out, P);
}